// Round 7
// baseline (547.008 us; speedup 1.0000x reference)
//
#include <hip/hip_runtime.h>
#include <math.h>

#define NPTS 12288
#define DIM 64
#define KNN 85
#define KSEL 86          // 85 neighbors + self
#define SAMPLE 2000
#define SSTRIDE 6        // deterministic sample: idx = 6*p, p in [0,2000)
#define GAMMA 0.5f
#define NT 512           // block size (8 waves): 2x waves per LDS allocation
#define WPB 8            // waves per block
#define VIT 6            // float4 dist iterations: 6*512*4 = 12288
#define NV 24            // d2 values per lane; MUST stay fully unrolled
#define VCAP 256         // block-level candidate capacity (~88-95 expected)
#define PT 64            // pearson tile
#define PPITCH 68        // padded LDS pitch (floats)
#define PBLK 1024        // pearson blocks: 32x32 tiles of 64

// ws layout: [0..36] double accumulators; offset 512: cx[N], cy[N], cz[N]
// acc: [0..4] pearson sums; [5..36] spread slots for local-loss partials

struct PearsonS {                  // ~37.9 KB; residency cap = 4 blocks/CU.
  float EpT[DIM][PPITCH];          // With 8 waves/block that is 32 waves/CU
  float EqT[DIM][PPITCH];          // (the HW max) vs 16 at 256 threads.
  float Cp[PT][4];
  float Cq[PT][4];
  float np_[PT];
  float nq_[PT];
  double wred[WPB][5];
};
struct KnnS {                      // ~3.3 KB
  unsigned h[256];                 // ONE block-level histogram
  unsigned bmax[WPB];              // per-wave max of m2
  unsigned long long vkey[VCAP];   // (u<<14)|j candidate keys
  unsigned long long thrkey;       // exact 86th-smallest key
  unsigned vcnt;
};
union SharedU { PearsonS p; KnnS k; };

__global__ void prep_kernel(const float* __restrict__ coord,
                            float* __restrict__ cx, float* __restrict__ cy,
                            float* __restrict__ cz) {
  int j = blockIdx.x * 256 + threadIdx.x;
  if (j < NPTS) {
    cx[j] = coord[3 * j];
    cy[j] = coord[3 * j + 1];
    cz[j] = coord[3 * j + 2];
  }
}

__device__ __forceinline__ void pearson_body(
    SharedU& sh, const float* __restrict__ emb, const float* __restrict__ coord,
    double* __restrict__ acc) {
  const int tid = threadIdx.x;
  const int tx = tid & 31;         // 32 col-groups x 2 cols
  const int ty = tid >> 5;         // 16 row-groups x 4 rows
  const int lane = tid & 63, wv = tid >> 6;
  const int pb = blockIdx.x;
  const int p0 = (pb >> 5) * PT, q0 = (pb & 31) * PT;

  #pragma unroll
  for (int e = tid; e < PT * DIM; e += NT) {
    int r = e >> 6, k = e & 63;
    int gp = (p0 + r < SAMPLE ? p0 + r : 0) * SSTRIDE;
    int gq = (q0 + r < SAMPLE ? q0 + r : 0) * SSTRIDE;
    sh.p.EpT[k][r] = emb[(size_t)gp * DIM + k];
    sh.p.EqT[k][r] = emb[(size_t)gq * DIM + k];
  }
  if (tid < PT) {
    int g = (p0 + tid < SAMPLE ? p0 + tid : 0) * SSTRIDE;
    sh.p.Cp[tid][0] = coord[3 * g]; sh.p.Cp[tid][1] = coord[3 * g + 1]; sh.p.Cp[tid][2] = coord[3 * g + 2];
  } else if (tid < 2 * PT) {
    int r = tid - PT;
    int g = (q0 + r < SAMPLE ? q0 + r : 0) * SSTRIDE;
    sh.p.Cq[r][0] = coord[3 * g]; sh.p.Cq[r][1] = coord[3 * g + 1]; sh.p.Cq[r][2] = coord[3 * g + 2];
  }
  __syncthreads();

  // row norms once per tile (ref uses the same |p|^2+|q|^2-2pq decomposition)
  if (tid < PT) {
    float a = 0.f;
    #pragma unroll 8
    for (int k = 0; k < DIM; ++k) { float v = sh.p.EpT[k][tid]; a += v * v; }
    sh.p.np_[tid] = a;
  } else if (tid < 2 * PT) {
    int r = tid - PT;
    float a = 0.f;
    #pragma unroll 8
    for (int k = 0; k < DIM; ++k) { float v = sh.p.EqT[k][r]; a += v * v; }
    sh.p.nq_[r] = a;
  }
  __syncthreads();

  // 4x2 micro-tile per thread (512 threads cover the 64x64 tile)
  float s[4][2] = {};
  #pragma unroll 8
  for (int k = 0; k < DIM; ++k) {
    float4 ep = *(const float4*)&sh.p.EpT[k][4 * ty];
    float2 eq = *(const float2*)&sh.p.EqT[k][2 * tx];
    float pa[4] = { ep.x, ep.y, ep.z, ep.w };
    float qa[2] = { eq.x, eq.y };
    #pragma unroll
    for (int a = 0; a < 4; ++a)
      #pragma unroll
      for (int b = 0; b < 2; ++b)
        s[a][b] += pa[a] * qa[b];
  }

  const float npr[4] = { sh.p.np_[4 * ty], sh.p.np_[4 * ty + 1], sh.p.np_[4 * ty + 2], sh.p.np_[4 * ty + 3] };
  const float nqr[2] = { sh.p.nq_[2 * tx], sh.p.nq_[2 * tx + 1] };

  double se = 0, sc = 0, se2 = 0, sc2 = 0, sec = 0;
  #pragma unroll
  for (int a = 0; a < 4; ++a)
    #pragma unroll
    for (int b = 0; b < 2; ++b) {
      int p = p0 + 4 * ty + a, q = q0 + 2 * tx + b;
      if (p < SAMPLE && q < SAMPLE) {
        float sq = fmaxf(npr[a] + nqr[b] - 2.f * s[a][b], 0.f);
        float ed = sqrtf(sq);
        float dx = sh.p.Cp[4 * ty + a][0] - sh.p.Cq[2 * tx + b][0];
        float dy = sh.p.Cp[4 * ty + a][1] - sh.p.Cq[2 * tx + b][1];
        float dz = sh.p.Cp[4 * ty + a][2] - sh.p.Cq[2 * tx + b][2];
        float cd = sqrtf(fmaxf(dx * dx + dy * dy + dz * dz, 0.f));
        se += (double)ed; sc += (double)cd;
        se2 += (double)ed * ed; sc2 += (double)cd * cd;
        sec += (double)ed * cd;
      }
    }

  double vals[5] = { se, sc, se2, sc2, sec };
  #pragma unroll
  for (int v = 0; v < 5; ++v) {
    #pragma unroll
    for (int off = 32; off > 0; off >>= 1) vals[v] += __shfl_xor(vals[v], off, 64);
  }
  if (lane == 0) {
    #pragma unroll
    for (int v = 0; v < 5; ++v) sh.p.wred[wv][v] = vals[v];
  }
  __syncthreads();
  if (tid < 5) {
    double sm = 0.0;
    #pragma unroll
    for (int w = 0; w < WPB; ++w) sm += sh.p.wred[w][tid];
    atomicAdd(&acc[tid], sm);
  }
}

__device__ __forceinline__ void knn_body(
    SharedU& sh, const float* __restrict__ emb, const float* __restrict__ cx,
    const float* __restrict__ cy, const float* __restrict__ cz,
    double* __restrict__ acc) {
  const int i = blockIdx.x - PBLK;
  const int tid = threadIdx.x;
  const int lane = tid & 63;
  const int wv = tid >> 6;

  const float qx = cx[i], qy = cy[i], qz = cz[i];
  const float4* CX4 = (const float4*)cx;
  const float4* CY4 = (const float4*)cy;
  const float4* CZ4 = (const float4*)cz;

  // 24 d2 values per thread in VGPRs. FULL unroll is mandatory: constant
  // indices -> register promotion (unroll 1 => scratch spill traffic).
  unsigned d2b[NV];
  #pragma unroll
  for (int it = 0; it < VIT; ++it) {
    int idx = it * NT + tid;
    float4 x4 = CX4[idx], y4 = CY4[idx], z4 = CZ4[idx];
    float dx, dy, dz;
    dx = qx - x4.x; dy = qy - y4.x; dz = qz - z4.x;
    d2b[4 * it + 0] = __float_as_uint(dx * dx + dy * dy + dz * dz);
    dx = qx - x4.y; dy = qy - y4.y; dz = qz - z4.y;
    d2b[4 * it + 1] = __float_as_uint(dx * dx + dy * dy + dz * dz);
    dx = qx - x4.z; dy = qy - y4.z; dz = qz - z4.z;
    d2b[4 * it + 2] = __float_as_uint(dx * dx + dy * dy + dz * dz);
    dx = qx - x4.w; dy = qy - y4.w; dz = qz - z4.w;
    d2b[4 * it + 3] = __float_as_uint(dx * dx + dy * dy + dz * dz);
  }
  // query-row fragment issued early: latency hidden under selection
  const float4 ei4 = ((const float4*)(emb + (size_t)i * DIM))[lane & 15];

  // per-lane two smallest (uint order == nonneg-float order)
  unsigned m1 = 0xFFFFFFFFu, m2 = 0xFFFFFFFFu;
  #pragma unroll
  for (int t = 0; t < NV; ++t) {
    unsigned u = d2b[t];
    unsigned hi = u > m1 ? u : m1;
    m1 = u < m1 ? u : m1;
    m2 = hi < m2 ? hi : m2;
  }
  // wave-max of m2 (all 128 m-values of this wave are <= it)
  unsigned M2w = m2;
  #pragma unroll
  for (int off = 32; off > 0; off >>= 1) {
    unsigned t2 = __shfl_xor((int)M2w, off, 64);
    M2w = t2 > M2w ? t2 : M2w;
  }
  if (lane == 0) sh.k.bmax[wv] = M2w;
  if (tid < 256) sh.k.h[tid] = 0;   // zero the single block-level histogram
  if (tid == 0) { sh.k.vcnt = 0; sh.k.thrkey = 0xFFFFFFFFFFFFFFFFULL; }
  __syncthreads();   // barrier 1: bmax + zeroed h + vcnt/thrkey init visible

  // ---- stage 1: ONE block-level 256-bin histogram over raw d2 <= B.
  // B = min over waves of (wave-max m2): the minimizing wave alone has 128
  // d2 values <= B, so cum reaches 86 within the binned range. T = upper
  // edge of the cum>=86 bin => count(d2<=T) >= 86 => T >= global 86th d2.
  unsigned Bu = sh.k.bmax[0];
  #pragma unroll
  for (int w = 1; w < WPB; ++w) {
    unsigned bw = sh.k.bmax[w];
    Bu = bw < Bu ? bw : Bu;
  }
  const float Bf = fmaxf(__uint_as_float(Bu), 1e-30f);
  const float sbin = 256.0f / Bf;

  #pragma unroll
  for (int t = 0; t < NV; ++t) {
    unsigned u = d2b[t];
    if (u <= Bu) {
      int bb = (int)(__uint_as_float(u) * sbin);
      bb = bb > 255 ? 255 : bb;
      atomicAdd(&sh.k.h[bb], 1u);
    }
  }
  __syncthreads();   // barrier 2: histogram complete

  // scan + pick, redundantly per wave from the shared h (no extra barrier)
  unsigned c0 = sh.k.h[4 * lane], c1 = sh.k.h[4 * lane + 1];
  unsigned c2 = sh.k.h[4 * lane + 2], c3 = sh.k.h[4 * lane + 3];
  unsigned lt = c0 + c1 + c2 + c3;
  unsigned incl = lt;
  #pragma unroll
  for (int off = 1; off < 64; off <<= 1) {
    unsigned t2 = __shfl_up(incl, off, 64);
    if (lane >= off) incl += t2;
  }
  unsigned excl = incl - lt;
  bool has = (lt > 0) && (excl < KSEL) && (KSEL <= incl);
  unsigned bin = 4 * lane, cum = excl;
  if (cum + c0 >= KSEL) { bin = 4 * lane; }
  else { cum += c0;
    if (cum + c1 >= KSEL) { bin = 4 * lane + 1; }
    else { cum += c1;
      if (cum + c2 >= KSEL) { bin = 4 * lane + 2; }
      else { bin = 4 * lane + 3; } } }
  unsigned long long bal = __ballot(has);
  int src = __ffsll((unsigned long long)bal) - 1;
  unsigned bsel = __shfl((int)bin, src, 64);
  float Uf = (float)(bsel + 1) * (Bf * (1.0f / 256.0f)) * 1.000002f;
  const unsigned T = __float_as_uint(Uf);

  // ---- stage 2: append candidates u <= T as 64-bit keys (u<<14)|j ----
  #pragma unroll
  for (int t = 0; t < NV; ++t) {
    unsigned u = d2b[t];
    if (u <= T) {
      unsigned pos = atomicAdd(&sh.k.vcnt, 1u);
      if (pos < VCAP) {
        unsigned pj = (unsigned)(4 * ((t >> 2) * NT + tid) + (t & 3));
        sh.k.vkey[pos] = ((unsigned long long)u << 14) | pj;
      }
    }
  }
  __syncthreads();   // barrier 3: candidate list visible
  const unsigned vc = sh.k.vcnt;
  const int tot = (int)(vc < VCAP ? vc : VCAP);

  // ---- stage 3: exact 86th-smallest key via rank counting; the rank-85
  // thread publishes its key (keys unique: index in low bits). Exact jax
  // top_k tie semantics: smaller distance first, then smaller index. ----
  if (tid < tot) {
    const unsigned long long kt = sh.k.vkey[tid];
    int rank = 0;
    for (int k = 0; k < tot; ++k) rank += (sh.k.vkey[k] < kt) ? 1 : 0;
    if (rank == KSEL - 1) sh.k.thrkey = kt;
  }
  __syncthreads();   // barrier 4: thrkey visible
  const unsigned long long thr64 = sh.k.thrkey;

  // ---- loss: 32 candidates per block-iteration (8 waves x 4 quarters) ----
  const int q = lane >> 4;
  const int l16 = lane & 15;
  float lsum = 0.f;
  for (int base = wv * 4; base < tot; base += 4 * WPB) { // wave-uniform trips
    int idx = base + q;
    bool valid = false;
    unsigned u = 0; int j = 0;
    if (idx < tot) {
      unsigned long long kk64 = sh.k.vkey[idx];
      u = (unsigned)(kk64 >> 14);
      j = (int)(kk64 & 0x3FFFu);
      valid = (kk64 <= thr64) && (j != i);
    }
    float s = 0.f;
    if (valid) {
      float4 e4 = ((const float4*)(emb + (size_t)j * DIM))[l16];
      float d0 = ei4.x - e4.x, d1 = ei4.y - e4.y;
      float d2 = ei4.z - e4.z, d3 = ei4.w - e4.w;
      s = d0 * d0 + d1 * d1 + d2 * d2 + d3 * d3;
    }
    s += __shfl_xor(s, 1, 64);
    s += __shfl_xor(s, 2, 64);
    s += __shfl_xor(s, 4, 64);
    s += __shfl_xor(s, 8, 64);
    if (valid && l16 == 0) {
      float td = sqrtf(__uint_as_float(u));
      float pd = sqrtf(fmaxf(s, 0.f));
      float diff = pd - td;
      lsum += diff * diff * expf(-GAMMA * td);
    }
  }
  #pragma unroll
  for (int off = 32; off > 0; off >>= 1) lsum += __shfl_xor(lsum, off, 64);
  // 32 spread slots: (i&3)*8 + wv in [0,32) -> acc[5..36]
  if (lane == 0) atomicAdd(&acc[5 + (i & 3) * 8 + wv], (double)lsum);
}

__global__ __launch_bounds__(NT) void fused_kernel(
    const float* __restrict__ emb, const float* __restrict__ coord,
    const float* __restrict__ cx, const float* __restrict__ cy,
    const float* __restrict__ cz, double* __restrict__ acc) {
  __shared__ SharedU sh;
  if (blockIdx.x < PBLK) {
    pearson_body(sh, emb, coord, acc);
  } else {
    knn_body(sh, emb, cx, cy, cz, acc);
  }
}

__global__ void finalize_kernel(const double* __restrict__ acc,
                                float* __restrict__ out) {
  double M = (double)SAMPLE * (double)SAMPLE;
  double med = acc[0] / M, mcd = acc[1] / M;
  double ve = acc[2] / M - med * med;
  double vc = acc[3] / M - mcd * mcd;
  double es = sqrt(ve + 1e-8);
  double cs = sqrt(vc + 1e-8);
  double cov = acc[4] / M - med * mcd;
  double pearson = cov / (es * cs + 1e-8);
  double lsum = 0.0;
  for (int s = 5; s < 37; ++s) lsum += acc[s];
  double local = lsum / ((double)NPTS * (double)KNN);
  out[0] = (float)((1.0 - pearson) + 0.5 * local);
}

extern "C" void kernel_launch(void* const* d_in, const int* in_sizes, int n_in,
                              void* d_out, int out_size, void* d_ws, size_t ws_size,
                              hipStream_t stream) {
  const float* emb = (const float*)d_in[0];    // (12288, 64) f32
  const float* coord = (const float*)d_in[1];  // (12288, 3) f32
  double* acc = (double*)d_ws;
  float* cx = (float*)((char*)d_ws + 512);     // 16B-aligned SoA coords
  float* cy = cx + NPTS;
  float* cz = cy + NPTS;

  hipMemsetAsync(d_ws, 0, 37 * sizeof(double), stream);

  prep_kernel<<<(NPTS + 255) / 256, 256, 0, stream>>>(coord, cx, cy, cz);

  fused_kernel<<<PBLK + NPTS, NT, 0, stream>>>(emb, coord, cx, cy, cz, acc);

  finalize_kernel<<<1, 1, 0, stream>>>(acc, (float*)d_out);
}

// Round 8
// 408.734 us; speedup vs baseline: 1.3383x; 1.3383x over previous
//
#include <hip/hip_runtime.h>
#include <math.h>

#define NPTS 12288
#define DIM 64
#define KNN 85
#define KSEL 86          // 85 neighbors + self
#define SAMPLE 2000
#define SSTRIDE 6        // deterministic sample: idx = 6*p, p in [0,2000)
#define GAMMA 0.5f
#define NT 256           // block size (4 waves) -- R7 proved 512 is 2x WORSE
#define WPB 4            // waves per block
#define QPB 2            // queries per knn block (amortize fixed overhead)
#define KBLK (NPTS / QPB)  // 6144 knn blocks
#define VIT 12           // float4 dist iterations: 12*256*4 = 12288
#define NV 48            // d2 values per lane per query; MUST stay fully unrolled
#define VCAP 256         // per-query candidate capacity (~88-95 expected)
#define PT 64            // pearson tile
#define PPITCH 68        // padded LDS pitch (floats)
#define PBLK 1024        // pearson blocks: 32x32 tiles of 64

// ws layout: [0..36] double accumulators; offset 512: cx[N], cy[N], cz[N]
// acc: [0..4] pearson sums; [5..36] spread slots for local-loss partials

struct PearsonS {                  // ~37.9 KB (full tiles: R4 proved k-slab worse)
  float EpT[DIM][PPITCH];
  float EqT[DIM][PPITCH];
  float Cp[PT][4];
  float Cq[PT][4];
  float np_[PT];
  float nq_[PT];
  double wred[WPB][5];
};
struct KnnS {                      // ~6.2 KB (two independent query pipelines)
  unsigned hA[256], hB[256];       // block-level histograms
  unsigned bmaxA[WPB], bmaxB[WPB];
  unsigned long long vkeyA[VCAP], vkeyB[VCAP];
  unsigned long long thrkeyA, thrkeyB;
  unsigned vcntA, vcntB;
};
union SharedU { PearsonS p; KnnS k; };

__global__ void prep_kernel(const float* __restrict__ coord,
                            float* __restrict__ cx, float* __restrict__ cy,
                            float* __restrict__ cz) {
  int j = blockIdx.x * 256 + threadIdx.x;
  if (j < NPTS) {
    cx[j] = coord[3 * j];
    cy[j] = coord[3 * j + 1];
    cz[j] = coord[3 * j + 2];
  }
}

__device__ __forceinline__ void pearson_body(
    SharedU& sh, const float* __restrict__ emb, const float* __restrict__ coord,
    double* __restrict__ acc) {
  const int tid = threadIdx.x;
  const int tx = tid & 15, ty = tid >> 4;
  const int lane = tid & 63, wv = tid >> 6;
  const int pb = blockIdx.x;
  const int p0 = (pb >> 5) * PT, q0 = (pb & 31) * PT;

  for (int e = tid; e < PT * DIM; e += 256) {
    int r = e >> 6, k = e & 63;
    int gp = (p0 + r < SAMPLE ? p0 + r : 0) * SSTRIDE;
    int gq = (q0 + r < SAMPLE ? q0 + r : 0) * SSTRIDE;
    sh.p.EpT[k][r] = emb[(size_t)gp * DIM + k];
    sh.p.EqT[k][r] = emb[(size_t)gq * DIM + k];
  }
  if (tid < PT) {
    int g = (p0 + tid < SAMPLE ? p0 + tid : 0) * SSTRIDE;
    sh.p.Cp[tid][0] = coord[3 * g]; sh.p.Cp[tid][1] = coord[3 * g + 1]; sh.p.Cp[tid][2] = coord[3 * g + 2];
  } else if (tid < 2 * PT) {
    int r = tid - PT;
    int g = (q0 + r < SAMPLE ? q0 + r : 0) * SSTRIDE;
    sh.p.Cq[r][0] = coord[3 * g]; sh.p.Cq[r][1] = coord[3 * g + 1]; sh.p.Cq[r][2] = coord[3 * g + 2];
  }
  __syncthreads();

  // row norms once per tile (ref uses the same |p|^2+|q|^2-2pq decomposition)
  if (tid < PT) {
    float a = 0.f;
    #pragma unroll 8
    for (int k = 0; k < DIM; ++k) { float v = sh.p.EpT[k][tid]; a += v * v; }
    sh.p.np_[tid] = a;
  } else if (tid < 2 * PT) {
    int r = tid - PT;
    float a = 0.f;
    #pragma unroll 8
    for (int k = 0; k < DIM; ++k) { float v = sh.p.EqT[k][r]; a += v * v; }
    sh.p.nq_[r] = a;
  }
  __syncthreads();

  float s[4][4] = {};
  #pragma unroll 8
  for (int k = 0; k < DIM; ++k) {
    float4 ep = *(const float4*)&sh.p.EpT[k][4 * ty];
    float4 eq = *(const float4*)&sh.p.EqT[k][4 * tx];
    float pa[4] = { ep.x, ep.y, ep.z, ep.w };
    float qa[4] = { eq.x, eq.y, eq.z, eq.w };
    #pragma unroll
    for (int a = 0; a < 4; ++a)
      #pragma unroll
      for (int b = 0; b < 4; ++b)
        s[a][b] += pa[a] * qa[b];
  }

  const float npr[4] = { sh.p.np_[4 * ty], sh.p.np_[4 * ty + 1], sh.p.np_[4 * ty + 2], sh.p.np_[4 * ty + 3] };
  const float nqr[4] = { sh.p.nq_[4 * tx], sh.p.nq_[4 * tx + 1], sh.p.nq_[4 * tx + 2], sh.p.nq_[4 * tx + 3] };

  double se = 0, sc = 0, se2 = 0, sc2 = 0, sec = 0;
  #pragma unroll
  for (int a = 0; a < 4; ++a)
    #pragma unroll
    for (int b = 0; b < 4; ++b) {
      int p = p0 + 4 * ty + a, q = q0 + 4 * tx + b;
      if (p < SAMPLE && q < SAMPLE) {
        float sq = fmaxf(npr[a] + nqr[b] - 2.f * s[a][b], 0.f);
        float ed = sqrtf(sq);
        float dx = sh.p.Cp[4 * ty + a][0] - sh.p.Cq[4 * tx + b][0];
        float dy = sh.p.Cp[4 * ty + a][1] - sh.p.Cq[4 * tx + b][1];
        float dz = sh.p.Cp[4 * ty + a][2] - sh.p.Cq[4 * tx + b][2];
        float cd = sqrtf(fmaxf(dx * dx + dy * dy + dz * dz, 0.f));
        se += (double)ed; sc += (double)cd;
        se2 += (double)ed * ed; sc2 += (double)cd * cd;
        sec += (double)ed * cd;
      }
    }

  double vals[5] = { se, sc, se2, sc2, sec };
  #pragma unroll
  for (int v = 0; v < 5; ++v) {
    #pragma unroll
    for (int off = 32; off > 0; off >>= 1) vals[v] += __shfl_xor(vals[v], off, 64);
  }
  if (lane == 0) {
    #pragma unroll
    for (int v = 0; v < 5; ++v) sh.p.wred[wv][v] = vals[v];
  }
  __syncthreads();
  if (tid < 5) {
    double sm = sh.p.wred[0][tid] + sh.p.wred[1][tid] + sh.p.wred[2][tid] + sh.p.wred[3][tid];
    atomicAdd(&acc[tid], sm);
  }
}

// one selection pipeline instance (scan of histogram, T, handled by caller);
// kept inline and duplicated A/B for register-static indexing.

__device__ __forceinline__ void knn_body(
    SharedU& sh, const float* __restrict__ emb, const float* __restrict__ cx,
    const float* __restrict__ cy, const float* __restrict__ cz,
    double* __restrict__ acc) {
  const int i0 = QPB * (blockIdx.x - PBLK);   // query A
  const int i1 = i0 + 1;                      // query B
  const int tid = threadIdx.x;
  const int lane = tid & 63;
  const int wv = tid >> 6;

  const float qxA = cx[i0], qyA = cy[i0], qzA = cz[i0];
  const float qxB = cx[i1], qyB = cy[i1], qzB = cz[i1];
  const float4* CX4 = (const float4*)cx;
  const float4* CY4 = (const float4*)cy;
  const float4* CZ4 = (const float4*)cz;

  // Combined scan: each coord float4 triple is loaded ONCE and serves BOTH
  // queries (the whole point of QPB=2: per-query L2 burst + barrier + tail
  // overhead halves). Full unroll mandatory (register promotion).
  unsigned dA[NV], dB[NV];
  unsigned m1A = 0xFFFFFFFFu, m2A = 0xFFFFFFFFu;
  unsigned m1B = 0xFFFFFFFFu, m2B = 0xFFFFFFFFu;
  #pragma unroll
  for (int it = 0; it < VIT; ++it) {
    int idx = it * NT + tid;
    float4 x4 = CX4[idx], y4 = CY4[idx], z4 = CZ4[idx];
    float px[4] = { x4.x, x4.y, x4.z, x4.w };
    float py[4] = { y4.x, y4.y, y4.z, y4.w };
    float pz[4] = { z4.x, z4.y, z4.z, z4.w };
    #pragma unroll
    for (int c = 0; c < 4; ++c) {
      float dxA = qxA - px[c], dyA = qyA - py[c], dzA = qzA - pz[c];
      unsigned uA = __float_as_uint(dxA * dxA + dyA * dyA + dzA * dzA);
      dA[4 * it + c] = uA;
      unsigned hiA = uA > m1A ? uA : m1A;
      m1A = uA < m1A ? uA : m1A;
      m2A = hiA < m2A ? hiA : m2A;
      float dxB = qxB - px[c], dyB = qyB - py[c], dzB = qzB - pz[c];
      unsigned uB = __float_as_uint(dxB * dxB + dyB * dyB + dzB * dzB);
      dB[4 * it + c] = uB;
      unsigned hiB = uB > m1B ? uB : m1B;
      m1B = uB < m1B ? uB : m1B;
      m2B = hiB < m2B ? hiB : m2B;
    }
  }

  // wave-max of m2 per query (all 128 m-values of this wave are <= it)
  unsigned MA = m2A, MB = m2B;
  #pragma unroll
  for (int off = 32; off > 0; off >>= 1) {
    unsigned tA = __shfl_xor((int)MA, off, 64);
    MA = tA > MA ? tA : MA;
    unsigned tB = __shfl_xor((int)MB, off, 64);
    MB = tB > MB ? tB : MB;
  }
  if (lane == 0) { sh.k.bmaxA[wv] = MA; sh.k.bmaxB[wv] = MB; }
  sh.k.hA[tid] = 0; sh.k.hB[tid] = 0;
  if (tid == 0) {
    sh.k.vcntA = 0; sh.k.vcntB = 0;
    sh.k.thrkeyA = 0xFFFFFFFFFFFFFFFFULL;
    sh.k.thrkeyB = 0xFFFFFFFFFFFFFFFFULL;
  }
  __syncthreads();   // barrier 1

  // ---- stage 1: block 256-bin linear histogram per query over raw d2 <= B.
  // B = min over waves of wave-max(m2): that wave alone has 128 d2 <= B, so
  // cum crosses 86. T = upper edge of crossing bin => T >= global 86th d2.
  unsigned BuA = sh.k.bmaxA[0], BuB = sh.k.bmaxB[0];
  #pragma unroll
  for (int w = 1; w < WPB; ++w) {
    unsigned a = sh.k.bmaxA[w]; BuA = a < BuA ? a : BuA;
    unsigned b = sh.k.bmaxB[w]; BuB = b < BuB ? b : BuB;
  }
  const float BfA = fmaxf(__uint_as_float(BuA), 1e-30f);
  const float BfB = fmaxf(__uint_as_float(BuB), 1e-30f);
  const float sbA = 256.0f / BfA;
  const float sbB = 256.0f / BfB;

  #pragma unroll
  for (int t = 0; t < NV; ++t) {
    unsigned uA = dA[t];
    if (uA <= BuA) {
      int bb = (int)(__uint_as_float(uA) * sbA);
      bb = bb > 255 ? 255 : bb;
      atomicAdd(&sh.k.hA[bb], 1u);
    }
    unsigned uB = dB[t];
    if (uB <= BuB) {
      int bb = (int)(__uint_as_float(uB) * sbB);
      bb = bb > 255 ? 255 : bb;
      atomicAdd(&sh.k.hB[bb], 1u);
    }
  }
  __syncthreads();   // barrier 2

  // scan + pick per query (redundant per wave, shuffle-only)
  unsigned TA, TB;
  {
    unsigned c0 = sh.k.hA[4 * lane], c1 = sh.k.hA[4 * lane + 1];
    unsigned c2 = sh.k.hA[4 * lane + 2], c3 = sh.k.hA[4 * lane + 3];
    unsigned lt = c0 + c1 + c2 + c3;
    unsigned incl = lt;
    #pragma unroll
    for (int off = 1; off < 64; off <<= 1) {
      unsigned t2 = __shfl_up(incl, off, 64);
      if (lane >= off) incl += t2;
    }
    unsigned excl = incl - lt;
    bool has = (lt > 0) && (excl < KSEL) && (KSEL <= incl);
    unsigned bin = 4 * lane, cum = excl;
    if (cum + c0 >= KSEL) { bin = 4 * lane; }
    else { cum += c0;
      if (cum + c1 >= KSEL) { bin = 4 * lane + 1; }
      else { cum += c1;
        if (cum + c2 >= KSEL) { bin = 4 * lane + 2; }
        else { bin = 4 * lane + 3; } } }
    unsigned long long bal = __ballot(has);
    int src = __ffsll((unsigned long long)bal) - 1;
    unsigned bsel = __shfl((int)bin, src, 64);
    TA = __float_as_uint((float)(bsel + 1) * (BfA * (1.0f / 256.0f)) * 1.000002f);
  }
  {
    unsigned c0 = sh.k.hB[4 * lane], c1 = sh.k.hB[4 * lane + 1];
    unsigned c2 = sh.k.hB[4 * lane + 2], c3 = sh.k.hB[4 * lane + 3];
    unsigned lt = c0 + c1 + c2 + c3;
    unsigned incl = lt;
    #pragma unroll
    for (int off = 1; off < 64; off <<= 1) {
      unsigned t2 = __shfl_up(incl, off, 64);
      if (lane >= off) incl += t2;
    }
    unsigned excl = incl - lt;
    bool has = (lt > 0) && (excl < KSEL) && (KSEL <= incl);
    unsigned bin = 4 * lane, cum = excl;
    if (cum + c0 >= KSEL) { bin = 4 * lane; }
    else { cum += c0;
      if (cum + c1 >= KSEL) { bin = 4 * lane + 1; }
      else { cum += c1;
        if (cum + c2 >= KSEL) { bin = 4 * lane + 2; }
        else { bin = 4 * lane + 3; } } }
    unsigned long long bal = __ballot(has);
    int src = __ffsll((unsigned long long)bal) - 1;
    unsigned bsel = __shfl((int)bin, src, 64);
    TB = __float_as_uint((float)(bsel + 1) * (BfB * (1.0f / 256.0f)) * 1.000002f);
  }

  // ---- stage 2: append candidates as 64-bit keys (u<<14)|j per query ----
  #pragma unroll
  for (int t = 0; t < NV; ++t) {
    unsigned pj = (unsigned)(4 * ((t >> 2) * NT + tid) + (t & 3));
    unsigned uA = dA[t];
    if (uA <= TA) {
      unsigned pos = atomicAdd(&sh.k.vcntA, 1u);
      if (pos < VCAP) sh.k.vkeyA[pos] = ((unsigned long long)uA << 14) | pj;
    }
    unsigned uB = dB[t];
    if (uB <= TB) {
      unsigned pos = atomicAdd(&sh.k.vcntB, 1u);
      if (pos < VCAP) sh.k.vkeyB[pos] = ((unsigned long long)uB << 14) | pj;
    }
  }
  // query-row fragments: issued here so latency hides under rank phase
  const float4 eiA = ((const float4*)(emb + (size_t)i0 * DIM))[lane & 15];
  const float4 eiB = ((const float4*)(emb + (size_t)i1 * DIM))[lane & 15];
  __syncthreads();   // barrier 3
  const int totA = (int)(sh.k.vcntA < VCAP ? sh.k.vcntA : VCAP);
  const int totB = (int)(sh.k.vcntB < VCAP ? sh.k.vcntB : VCAP);

  // ---- stage 3: exact 86th-smallest key via rank counting (jax top_k tie
  // semantics: distance then index). Rank-85 thread publishes its key. ----
  if (tid < totA) {
    const unsigned long long kt = sh.k.vkeyA[tid];
    int rank = 0;
    for (int k = 0; k < totA; ++k) rank += (sh.k.vkeyA[k] < kt) ? 1 : 0;
    if (rank == KSEL - 1) sh.k.thrkeyA = kt;
  }
  if (tid < totB) {
    const unsigned long long kt = sh.k.vkeyB[tid];
    int rank = 0;
    for (int k = 0; k < totB; ++k) rank += (sh.k.vkeyB[k] < kt) ? 1 : 0;
    if (rank == KSEL - 1) sh.k.thrkeyB = kt;
  }
  __syncthreads();   // barrier 4
  const unsigned long long thrA = sh.k.thrkeyA;
  const unsigned long long thrB = sh.k.thrkeyB;

  // ---- loss: 16 candidates per block-iteration per query ----
  const int q = lane >> 4;
  const int l16 = lane & 15;
  float lsumA = 0.f, lsumB = 0.f;
  for (int base = wv * 4; base < totA; base += 16) {
    int idx = base + q;
    bool valid = false;
    unsigned u = 0; int j = 0;
    if (idx < totA) {
      unsigned long long kk = sh.k.vkeyA[idx];
      u = (unsigned)(kk >> 14);
      j = (int)(kk & 0x3FFFu);
      valid = (kk <= thrA) && (j != i0);
    }
    float s = 0.f;
    if (valid) {
      float4 e4 = ((const float4*)(emb + (size_t)j * DIM))[l16];
      float d0 = eiA.x - e4.x, d1 = eiA.y - e4.y;
      float d2 = eiA.z - e4.z, d3 = eiA.w - e4.w;
      s = d0 * d0 + d1 * d1 + d2 * d2 + d3 * d3;
    }
    s += __shfl_xor(s, 1, 64);
    s += __shfl_xor(s, 2, 64);
    s += __shfl_xor(s, 4, 64);
    s += __shfl_xor(s, 8, 64);
    if (valid && l16 == 0) {
      float td = sqrtf(__uint_as_float(u));
      float pd = sqrtf(fmaxf(s, 0.f));
      float diff = pd - td;
      lsumA += diff * diff * expf(-GAMMA * td);
    }
  }
  for (int base = wv * 4; base < totB; base += 16) {
    int idx = base + q;
    bool valid = false;
    unsigned u = 0; int j = 0;
    if (idx < totB) {
      unsigned long long kk = sh.k.vkeyB[idx];
      u = (unsigned)(kk >> 14);
      j = (int)(kk & 0x3FFFu);
      valid = (kk <= thrB) && (j != i1);
    }
    float s = 0.f;
    if (valid) {
      float4 e4 = ((const float4*)(emb + (size_t)j * DIM))[l16];
      float d0 = eiB.x - e4.x, d1 = eiB.y - e4.y;
      float d2 = eiB.z - e4.z, d3 = eiB.w - e4.w;
      s = d0 * d0 + d1 * d1 + d2 * d2 + d3 * d3;
    }
    s += __shfl_xor(s, 1, 64);
    s += __shfl_xor(s, 2, 64);
    s += __shfl_xor(s, 4, 64);
    s += __shfl_xor(s, 8, 64);
    if (valid && l16 == 0) {
      float td = sqrtf(__uint_as_float(u));
      float pd = sqrtf(fmaxf(s, 0.f));
      float diff = pd - td;
      lsumB += diff * diff * expf(-GAMMA * td);
    }
  }
  #pragma unroll
  for (int off = 32; off > 0; off >>= 1) {
    lsumA += __shfl_xor(lsumA, off, 64);
    lsumB += __shfl_xor(lsumB, off, 64);
  }
  if (lane == 0) {
    atomicAdd(&acc[5 + (i0 & 7) * 4 + wv], (double)lsumA);
    atomicAdd(&acc[5 + (i1 & 7) * 4 + wv], (double)lsumB);
  }
}

__global__ __launch_bounds__(NT) void fused_kernel(
    const float* __restrict__ emb, const float* __restrict__ coord,
    const float* __restrict__ cx, const float* __restrict__ cy,
    const float* __restrict__ cz, double* __restrict__ acc) {
  __shared__ SharedU sh;
  if (blockIdx.x < PBLK) {
    pearson_body(sh, emb, coord, acc);
  } else {
    knn_body(sh, emb, cx, cy, cz, acc);
  }
}

__global__ void finalize_kernel(const double* __restrict__ acc,
                                float* __restrict__ out) {
  double M = (double)SAMPLE * (double)SAMPLE;
  double med = acc[0] / M, mcd = acc[1] / M;
  double ve = acc[2] / M - med * med;
  double vc = acc[3] / M - mcd * mcd;
  double es = sqrt(ve + 1e-8);
  double cs = sqrt(vc + 1e-8);
  double cov = acc[4] / M - med * mcd;
  double pearson = cov / (es * cs + 1e-8);
  double lsum = 0.0;
  for (int s = 5; s < 37; ++s) lsum += acc[s];
  double local = lsum / ((double)NPTS * (double)KNN);
  out[0] = (float)((1.0 - pearson) + 0.5 * local);
}

extern "C" void kernel_launch(void* const* d_in, const int* in_sizes, int n_in,
                              void* d_out, int out_size, void* d_ws, size_t ws_size,
                              hipStream_t stream) {
  const float* emb = (const float*)d_in[0];    // (12288, 64) f32
  const float* coord = (const float*)d_in[1];  // (12288, 3) f32
  double* acc = (double*)d_ws;
  float* cx = (float*)((char*)d_ws + 512);     // 16B-aligned SoA coords
  float* cy = cx + NPTS;
  float* cz = cy + NPTS;

  hipMemsetAsync(d_ws, 0, 37 * sizeof(double), stream);

  prep_kernel<<<(NPTS + 255) / 256, 256, 0, stream>>>(coord, cx, cy, cz);

  fused_kernel<<<PBLK + KBLK, NT, 0, stream>>>(emb, coord, cx, cy, cz, acc);

  finalize_kernel<<<1, 1, 0, stream>>>(acc, (float*)d_out);
}